// Round 3
// baseline (1667.303 us; speedup 1.0000x reference)
//
#include <hip/hip_runtime.h>
#include <hip/hip_bf16.h>

// MultiAttention: S=1024, B=8, D=1024, H=8
// Round 3: QKV fused per 4-head group into one 8192x12288x1024 GEMM running the
// 256^2 8-phase schedule (T2 swizzle + T3/T4 counted vmcnt + T5 setprio).
// scores/PV/outproj stay on the proven 128^2 kernel. ws peak 353 MiB.

typedef __attribute__((ext_vector_type(8))) __bf16 bf16x8;
typedef __attribute__((ext_vector_type(4))) float f32x4;

__device__ __forceinline__ unsigned short f2bf(float f) {
  union { float f; unsigned u; } x; x.f = f;
  unsigned r = x.u + 0x7fffu + ((x.u >> 16) & 1u);   // RNE
  return (unsigned short)(r >> 16);
}

__device__ __forceinline__ void gload16(const void* g, void* l) {
  __builtin_amdgcn_global_load_lds(
      (const __attribute__((address_space(1))) void*)g,
      (__attribute__((address_space(3))) void*)l, 16, 0, 0);
}

#define SBAR()  do { __builtin_amdgcn_sched_barrier(0); __builtin_amdgcn_s_barrier(); \
                     __builtin_amdgcn_sched_barrier(0); } while (0)
#define LGKM0() do { asm volatile("s_waitcnt lgkmcnt(0)" ::: "memory"); \
                     __builtin_amdgcn_sched_barrier(0); } while (0)
#define VMC4()  do { asm volatile("s_waitcnt vmcnt(4)" ::: "memory"); \
                     __builtin_amdgcn_sched_barrier(0); } while (0)

// ================= 256x256 8-phase NT GEMM (bf16 out, +bias) ==================
// C[M][N] = A[M][K] @ B[N][K]^T + bias[col].  K % 128 == 0.  grid.x = MT*NT8,
// 512 threads. LDS 128 KiB: buf{0,1} x { A.h0,A.h1,B.h0,B.h1 } x 16 KiB.
// T2 swizzle: LDS byte = logical ^ ((row&7)<<4); staged via inverse-swz source.

struct Frags { bf16x8 aF[4][2]; bf16x8 b0F[2][2]; bf16x8 b1F[2][2]; };

template<int QUAD>
__device__ __forceinline__ void qreads(const char* sm, int bb, int aRow, int bRow,
                                       int kx0, int kx1, Frags& fr)
{
  if constexpr (QUAD == 0) {
#pragma unroll
    for (int m = 0; m < 4; ++m) {
      fr.aF[m][0] = *(const bf16x8*)(sm + bb + aRow + m * 2048 + kx0);
      fr.aF[m][1] = *(const bf16x8*)(sm + bb + aRow + m * 2048 + kx1);
    }
#pragma unroll
    for (int n = 0; n < 2; ++n) {
      fr.b0F[n][0] = *(const bf16x8*)(sm + bb + bRow + n * 2048 + kx0);
      fr.b0F[n][1] = *(const bf16x8*)(sm + bb + bRow + n * 2048 + kx1);
    }
  } else if constexpr (QUAD == 1) {
#pragma unroll
    for (int n = 0; n < 2; ++n) {
      fr.b1F[n][0] = *(const bf16x8*)(sm + bb + bRow + (2 + n) * 2048 + kx0);
      fr.b1F[n][1] = *(const bf16x8*)(sm + bb + bRow + (2 + n) * 2048 + kx1);
    }
  } else if constexpr (QUAD == 2) {
#pragma unroll
    for (int m = 0; m < 4; ++m) {
      fr.aF[m][0] = *(const bf16x8*)(sm + bb + aRow + (4 + m) * 2048 + kx0);
      fr.aF[m][1] = *(const bf16x8*)(sm + bb + aRow + (4 + m) * 2048 + kx1);
    }
  }
}

template<int QUAD>
__device__ __forceinline__ void qmfma(f32x4 acc[8][4], Frags& fr)
{
  constexpr int mo = (QUAD >= 2) ? 4 : 0;
  constexpr int no = (QUAD == 1 || QUAD == 2) ? 2 : 0;
  __builtin_amdgcn_s_setprio(1);
#pragma unroll
  for (int m = 0; m < 4; ++m)
#pragma unroll
    for (int n = 0; n < 2; ++n)
#pragma unroll
      for (int ks = 0; ks < 2; ++ks) {
        const bf16x8 bv = (no == 0) ? fr.b0F[n][ks] : fr.b1F[n][ks];
        acc[mo + m][no + n] =
            __builtin_amdgcn_mfma_f32_16x16x32_bf16(fr.aF[m][ks], bv, acc[mo + m][no + n], 0, 0, 0);
      }
  __builtin_amdgcn_s_setprio(0);
  __builtin_amdgcn_sched_barrier(0);
}

__global__ __launch_bounds__(512, 2)
void gemm256_nt(const unsigned short* __restrict__ A,
                const unsigned short* __restrict__ B,
                unsigned short* __restrict__ C,
                const float* __restrict__ bias,
                int K, long lda, long ldb, long ldc, int MT)
{
  __shared__ __align__(16) char sm[131072];

  // XCD-aware bijective swizzle (grid.x % 8 == 0), mt fastest within chunk.
  const int nwg = gridDim.x;
  const int swz = (blockIdx.x & 7) * (nwg >> 3) + (blockIdx.x >> 3);
  const int mt = swz % MT, nt = swz / MT;

  const unsigned short* Ablk = A + (long)mt * 256 * lda;
  const unsigned short* Bblk = B + (long)nt * 256 * ldb;

  const int tid  = threadIdx.x;
  const int lane = tid & 63;
  const int w    = tid >> 6;
  const int wr   = w >> 2, wc = w & 3;       // 2M x 4N waves

  // staging per-thread geometry (j=0: rows 0-63, j=1: rows 64-127 of half-tile)
  const int rA  = tid >> 3;
  const int cSw = (tid ^ (tid >> 3)) & 7;    // inverse-swizzled 16B slot

  // ds-read bases (bytes within one 64 KiB buffer)
  const int aRow = wr * 16384 + (lane & 15) * 128;
  const int bRow = 32768 + (wc >> 1) * 16384 + ((wc & 1) * 64 + (lane & 15)) * 128;
  const int kq = (lane >> 4) * 16, sw = (lane & 7) << 4;
  const int kx0 = kq ^ sw;
  const int kx1 = (64 + kq) ^ sw;

  const int NT = K >> 6;        // BK=64 tiles
  const int NIT = NT >> 1;

  f32x4 acc[8][4] = {};
  Frags fr;

  auto stageA = [&](int half, int kt, int region) {
    const unsigned short* g = Ablk + ((long)(half * 128) + rA) * lda + (long)kt * 64 + cSw * 8;
    gload16(g,            sm + region + tid * 16);
    gload16(g + 64 * lda, sm + region + 8192 + tid * 16);
  };
  auto stageB = [&](int half, int kt, int region) {
    const unsigned short* g = Bblk + ((long)(half * 128) + rA) * ldb + (long)kt * 64 + cSw * 8;
    gload16(g,            sm + region + tid * 16);
    gload16(g + 64 * ldb, sm + region + 8192 + tid * 16);
  };

  // prologue: tile0 -> buf0 (all 4 halves), tile1.B -> buf1
  stageA(0, 0, 0);
  stageA(1, 0, 16384);
  stageB(0, 0, 32768);
  stageB(1, 0, 49152);
  stageB(0, 1, 65536 + 32768);
  stageB(1, 1, 65536 + 49152);
  VMC4();           // tile0 landed (tile1.B may be outstanding)
  SBAR();

#pragma unroll 1
  for (int it = 0; it < NIT; ++it) {
    const int kt1 = 2 * it + 1;
    const int kt2a = 2 * it + 2, kt2 = kt2a < NT ? kt2a : NT - 1;
    const int kt3a = 2 * it + 3, kt3 = kt3a < NT ? kt3a : NT - 1;

    // ---- K-tile 2it from buf0 ----
    qreads<0>(sm, 0, aRow, bRow, kx0, kx1, fr);
    stageA(0, kt1, 65536);                       // buf1.A.h0 (tile 2it+1)
    SBAR(); LGKM0(); qmfma<0>(acc, fr); SBAR();

    qreads<1>(sm, 0, aRow, bRow, kx0, kx1, fr);
    stageA(1, kt1, 65536 + 16384);               // buf1.A.h1
    SBAR(); LGKM0(); qmfma<1>(acc, fr); SBAR();

    qreads<2>(sm, 0, aRow, bRow, kx0, kx1, fr);
    stageB(0, kt2, 32768);                       // buf0.B.h0 (tile 2it+2)
    SBAR(); LGKM0(); qmfma<2>(acc, fr); SBAR();

    stageB(1, kt2, 49152);                       // buf0.B.h1
    SBAR(); LGKM0(); qmfma<3>(acc, fr);
    VMC4();                                      // tile 2it+1 fully landed
    SBAR();

    // ---- K-tile 2it+1 from buf1 ----
    qreads<0>(sm, 65536, aRow, bRow, kx0, kx1, fr);
    stageA(0, kt2, 0);                           // buf0.A.h0 (tile 2it+2)
    SBAR(); LGKM0(); qmfma<0>(acc, fr); SBAR();

    qreads<1>(sm, 65536, aRow, bRow, kx0, kx1, fr);
    stageA(1, kt2, 16384);                       // buf0.A.h1
    SBAR(); LGKM0(); qmfma<1>(acc, fr); SBAR();

    qreads<2>(sm, 65536, aRow, bRow, kx0, kx1, fr);
    stageB(0, kt3, 65536 + 32768);               // buf1.B.h0 (tile 2it+3)
    SBAR(); LGKM0(); qmfma<2>(acc, fr); SBAR();

    stageB(1, kt3, 65536 + 49152);               // buf1.B.h1
    SBAR(); LGKM0(); qmfma<3>(acc, fr);
    VMC4();                                      // tile 2it+2 fully landed
    SBAR();
  }

  // epilogue: C/D layout col = lane&15, row = (lane>>4)*4 + j
  const long crow0 = (long)mt * 256 + wr * 128;
  const long ccol0 = (long)nt * 256 + wc * 64;
#pragma unroll
  for (int m = 0; m < 8; ++m)
#pragma unroll
    for (int n = 0; n < 4; ++n) {
      const long col = ccol0 + n * 16 + (lane & 15);
      const float badd = bias[col];
#pragma unroll
      for (int j = 0; j < 4; ++j) {
        const long row = crow0 + m * 16 + (lane >> 4) * 4 + j;
        C[row * ldc + col] = f2bf(acc[m][n][j] + badd);
      }
    }
}

// ================= 128x128 NT GEMM (proven round-2 kernel) ====================
// CMODE: 0 = fp32 store, 1 = bf16 store, 2 = fp32 accumulate
template<int CMODE, int HAS_BIAS>
__global__ __launch_bounds__(256, 2)
void gemm_nt(const unsigned short* __restrict__ A,
             const unsigned short* __restrict__ B,
             void* __restrict__ C,
             const float* __restrict__ bias,
             float alpha, int K,
             long lda, long ldb, long ldc,
             long offA_b, long offB_b, long offC_b)
{
  __shared__ __align__(16) unsigned short As[128 * 32];
  __shared__ __align__(16) unsigned short Bs[128 * 32];

  const int z = blockIdx.z;
  const unsigned short* Ab = A + z * offA_b + (long)blockIdx.x * 128 * lda;
  const unsigned short* Bb = B + z * offB_b + (long)blockIdx.y * 128 * ldb;

  const int tid  = threadIdx.x;
  const int lane = tid & 63;
  const int w    = tid >> 6;
  const int wr   = w >> 1, wc = w & 1;

  const int c0 = tid, c1 = tid + 256;
  const int r0 = c0 >> 2, q0 = (c0 & 3) * 8;
  const int r1 = c1 >> 2, q1 = (c1 & 3) * 8;
  const unsigned short* gA0 = Ab + (long)r0 * lda + q0;
  const unsigned short* gA1 = Ab + (long)r1 * lda + q1;
  const unsigned short* gB0 = Bb + (long)r0 * ldb + q0;
  const unsigned short* gB1 = Bb + (long)r1 * ldb + q1;

  f32x4 acc[4][4] = {};

  const int arow = wr * 64 + (lane & 15);
  const int brow = wc * 64 + (lane & 15);
  const int kof  = (lane >> 4) * 8;

  for (int kt = 0; kt < K; kt += 32) {
    gload16(gA0, As + c0 * 8);
    gload16(gA1, As + c1 * 8);
    gload16(gB0, Bs + c0 * 8);
    gload16(gB1, Bs + c1 * 8);
    gA0 += 32; gA1 += 32; gB0 += 32; gB1 += 32;
    __syncthreads();

    bf16x8 af[4], bg[4];
#pragma unroll
    for (int m = 0; m < 4; ++m)
      af[m] = *(const bf16x8*)(As + (arow + m * 16) * 32 + kof);
#pragma unroll
    for (int n = 0; n < 4; ++n)
      bg[n] = *(const bf16x8*)(Bs + (brow + n * 16) * 32 + kof);

#pragma unroll
    for (int m = 0; m < 4; ++m)
#pragma unroll
      for (int n = 0; n < 4; ++n)
        acc[m][n] = __builtin_amdgcn_mfma_f32_16x16x32_bf16(af[m], bg[n], acc[m][n], 0, 0, 0);
    __syncthreads();
  }

  const long crow0 = (long)blockIdx.x * 128 + wr * 64;
  const long ccol0 = (long)blockIdx.y * 128 + wc * 64;
  const long cbase = z * offC_b;

#pragma unroll
  for (int m = 0; m < 4; ++m) {
#pragma unroll
    for (int n = 0; n < 4; ++n) {
      const long col = ccol0 + n * 16 + (lane & 15);
      const float badd = HAS_BIAS ? bias[col] : 0.0f;
#pragma unroll
      for (int j = 0; j < 4; ++j) {
        const long row = crow0 + m * 16 + (lane >> 4) * 4 + j;
        const float v = acc[m][n][j] * alpha + badd;
        const long idx = cbase + row * ldc + col;
        if (CMODE == 1)      ((unsigned short*)C)[idx] = f2bf(v);
        else if (CMODE == 2) ((float*)C)[idx] += v;
        else                 ((float*)C)[idx] = v;
      }
    }
  }
}

// ---------------- softmax over rows of 1024 (fp32 in, bf16 out) ---------------
__global__ __launch_bounds__(256)
void softmax_k(const float* __restrict__ SC, unsigned short* __restrict__ P)
{
  const long row = blockIdx.x;
  const float* s = SC + (row << 10);
  unsigned short* p = P + (row << 10);
  const int tid = threadIdx.x;

  float4 v = ((const float4*)s)[tid];
  float mx = fmaxf(fmaxf(v.x, v.y), fmaxf(v.z, v.w));
#pragma unroll
  for (int o = 32; o >= 1; o >>= 1) mx = fmaxf(mx, __shfl_xor(mx, o));
  __shared__ float red[8];
  const int w = tid >> 6, lane = tid & 63;
  if (lane == 0) red[w] = mx;
  __syncthreads();
  mx = fmaxf(fmaxf(red[0], red[1]), fmaxf(red[2], red[3]));

  float e0 = __expf(v.x - mx), e1 = __expf(v.y - mx);
  float e2 = __expf(v.z - mx), e3 = __expf(v.w - mx);
  float sum = e0 + e1 + e2 + e3;
#pragma unroll
  for (int o = 32; o >= 1; o >>= 1) sum += __shfl_xor(sum, o);
  if (lane == 0) red[4 + w] = sum;
  __syncthreads();
  sum = red[4] + red[5] + red[6] + red[7];
  const float inv = 1.0f / sum;

  ushort4 o4;
  o4.x = f2bf(e0 * inv); o4.y = f2bf(e1 * inv);
  o4.z = f2bf(e2 * inv); o4.w = f2bf(e3 * inv);
  ((ushort4*)p)[tid] = o4;
}

// ---- V transpose: VT[b][e][t] = src[b*bStr + t*tStr + e] ---------------------
__global__ __launch_bounds__(256)
void transpose_v(const unsigned short* __restrict__ src, unsigned short* __restrict__ VT,
                 long tStr, long bStr)
{
  const int b = blockIdx.z;
  __shared__ unsigned short tile[32][33];
  const int t0 = blockIdx.x * 32, e0 = blockIdx.y * 32;
  const int tx = threadIdx.x & 31, ty = threadIdx.x >> 5;
#pragma unroll
  for (int i = 0; i < 4; ++i) {
    const int tr = ty + i * 8;
    tile[tr][tx] = src[(long)b * bStr + (long)(t0 + tr) * tStr + e0 + tx];
  }
  __syncthreads();
#pragma unroll
  for (int i = 0; i < 4; ++i) {
    const int er = ty + i * 8;
    VT[(long)b * 1048576 + (long)(e0 + er) * 1024 + t0 + tx] = tile[tx][er];
  }
}

// ---------------- converters / init -------------------------------------------
__global__ __launch_bounds__(256)
void conv_bf16(const float* __restrict__ in, unsigned short* __restrict__ out, long n4)
{
  const long i = (long)blockIdx.x * 256 + threadIdx.x;
  if (i >= n4) return;
  const float4 v = ((const float4*)in)[i];
  ushort4 o; o.x = f2bf(v.x); o.y = f2bf(v.y); o.z = f2bf(v.z); o.w = f2bf(v.w);
  ((ushort4*)out)[i] = o;
}

__global__ __launch_bounds__(256)
void bias_sum_k(const float* __restrict__ b_out, float* __restrict__ bsum)
{
  const int f = blockIdx.x * 256 + threadIdx.x;
  if (f < 1024) {
    float s = 0.f;
#pragma unroll
    for (int h = 0; h < 8; ++h) s += b_out[h * 1024 + f];
    bsum[f] = s;
  }
}

__global__ __launch_bounds__(256)
void out_init_k(float* __restrict__ out, const float* __restrict__ bsum)
{
  const long i = (long)blockIdx.x * 256 + threadIdx.x;
  ((float4*)out)[i] = ((const float4*)bsum)[i & 255];
}

// ---------------- launch ------------------------------------------------------
extern "C" void kernel_launch(void* const* d_in, const int* in_sizes, int n_in,
                              void* d_out, int out_size, void* d_ws, size_t ws_size,
                              hipStream_t stream)
{
  const float* x     = (const float*)d_in[0];
  const float* w_in  = (const float*)d_in[1];
  const float* b_in  = (const float*)d_in[2];
  const float* w_out = (const float*)d_in[3];
  const float* b_out = (const float*)d_in[4];
  float* out = (float*)d_out;

  char* ws = (char*)d_ws;
  const long MB = 1ll << 20;
  unsigned short* Xb    = (unsigned short*)(ws);              // 16 MiB
  unsigned short* WbAll = (unsigned short*)(ws + 16 * MB);    // 48 MiB
  unsigned short* WoAll = (unsigned short*)(ws + 64 * MB);    // 16 MiB
  float*          bsum  = (float*)         (ws + 80 * MB);    // 4 KiB
  unsigned short* QKVg  = (unsigned short*)(ws + 81 * MB);    // 192 MiB
  float*          SC    = (float*)         (ws + 273 * MB);   // 32 MiB
  unsigned short* P     = (unsigned short*)(ws + 305 * MB);   // 16 MiB
  unsigned short* VT    = (unsigned short*)(ws + 321 * MB);   // 16 MiB
  unsigned short* Obuf  = (unsigned short*)(ws + 337 * MB);   // 16 MiB -> 353 MiB

  dim3 blk(256);

  conv_bf16 <<<8192,  blk, 0, stream>>>(x,     Xb,    2097152);
  conv_bf16 <<<24576, blk, 0, stream>>>(w_in,  WbAll, 6291456);
  conv_bf16 <<<8192,  blk, 0, stream>>>(w_out, WoAll, 2097152);
  bias_sum_k<<<4,     blk, 0, stream>>>(b_out, bsum);
  out_init_k<<<8192,  blk, 0, stream>>>(out, bsum);

  for (int g = 0; g < 2; ++g) {
    // QKVg[sb][hh*3072 + sec*1024 + e] for heads g*4..g*4+3 (one 8-phase GEMM)
    gemm256_nt<<<1536, dim3(512), 0, stream>>>(
        Xb, WbAll + (long)g * 12582912, QKVg, b_in + (long)g * 12288,
        1024, 1024, 1024, 12288, 32);

    for (int hh = 0; hh < 4; ++hh) {
      const int h = g * 4 + hh;
      const unsigned short* Qh = QKVg + hh * 3072;
      const unsigned short* Kh = QKVg + hh * 3072 + 1024;
      const unsigned short* Vh = QKVg + hh * 3072 + 2048;

      dim3 g2(8, 8, 8);
      // SC[b][s][t] = (Q_b K_b^T)/32, fp32
      gemm_nt<0,0><<<g2, blk, 0, stream>>>(Qh, Kh, SC, nullptr, 0.03125f, 1024,
          98304, 98304, 1024,  12288, 12288, 1048576);

      softmax_k  <<<8192, blk, 0, stream>>>(SC, P);
      transpose_v<<<dim3(32, 32, 8), blk, 0, stream>>>(Vh, VT, 98304, 12288);

      // O[(s*8+b)*1024 + e] = sum_t P[b][s][t] VT[b][e][t]
      gemm_nt<1,0><<<g2, blk, 0, stream>>>(P, VT, Obuf, nullptr, 1.0f, 1024,
          1024, 1024, 8192,  1048576, 1048576, 1024);

      // out += O @ Wo[h]^T
      gemm_nt<2,0><<<dim3(64, 8, 1), blk, 0, stream>>>(Obuf, WoAll + (long)h * 1048576,
          out, nullptr, 1.0f, 1024,  1024, 1024, 1024,  0, 0, 0);
    }
  }
}

// Round 5
// 1299.177 us; speedup vs baseline: 1.2834x; 1.2834x over previous
//
#include <hip/hip_runtime.h>
#include <hip/hip_bf16.h>

// MultiAttention: S=1024, B=8, D=1024, H=8
// Round 5: round-4 structure with the PV C-layout fix (ldc=65536: Ocat rows are
// sb-major with stride 8192, so s-stride is 65536). ws peak 365 MiB.

typedef __attribute__((ext_vector_type(8))) __bf16 bf16x8;
typedef __attribute__((ext_vector_type(4))) float f32x4;

__device__ __forceinline__ unsigned short f2bf(float f) {
  union { float f; unsigned u; } x; x.f = f;
  unsigned r = x.u + 0x7fffu + ((x.u >> 16) & 1u);   // RNE
  return (unsigned short)(r >> 16);
}

__device__ __forceinline__ void gload16(const void* g, void* l) {
  __builtin_amdgcn_global_load_lds(
      (const __attribute__((address_space(1))) void*)g,
      (__attribute__((address_space(3))) void*)l, 16, 0, 0);
}

#define SBAR()  do { __builtin_amdgcn_sched_barrier(0); __builtin_amdgcn_s_barrier(); \
                     __builtin_amdgcn_sched_barrier(0); } while (0)
#define LGKM0() do { asm volatile("s_waitcnt lgkmcnt(0)" ::: "memory"); \
                     __builtin_amdgcn_sched_barrier(0); } while (0)
#define VMC4()  do { asm volatile("s_waitcnt vmcnt(4)" ::: "memory"); \
                     __builtin_amdgcn_sched_barrier(0); } while (0)

// ================= 256x256 8-phase NT GEMM (bf16 out, +bias) ==================
struct Frags { bf16x8 aF[4][2]; bf16x8 b0F[2][2]; bf16x8 b1F[2][2]; };

template<int QUAD>
__device__ __forceinline__ void qreads(const char* sm, int bb, int aRow, int bRow,
                                       int kx0, int kx1, Frags& fr)
{
  if constexpr (QUAD == 0) {
#pragma unroll
    for (int m = 0; m < 4; ++m) {
      fr.aF[m][0] = *(const bf16x8*)(sm + bb + aRow + m * 2048 + kx0);
      fr.aF[m][1] = *(const bf16x8*)(sm + bb + aRow + m * 2048 + kx1);
    }
#pragma unroll
    for (int n = 0; n < 2; ++n) {
      fr.b0F[n][0] = *(const bf16x8*)(sm + bb + bRow + n * 2048 + kx0);
      fr.b0F[n][1] = *(const bf16x8*)(sm + bb + bRow + n * 2048 + kx1);
    }
  } else if constexpr (QUAD == 1) {
#pragma unroll
    for (int n = 0; n < 2; ++n) {
      fr.b1F[n][0] = *(const bf16x8*)(sm + bb + bRow + (2 + n) * 2048 + kx0);
      fr.b1F[n][1] = *(const bf16x8*)(sm + bb + bRow + (2 + n) * 2048 + kx1);
    }
  } else if constexpr (QUAD == 2) {
#pragma unroll
    for (int m = 0; m < 4; ++m) {
      fr.aF[m][0] = *(const bf16x8*)(sm + bb + aRow + (4 + m) * 2048 + kx0);
      fr.aF[m][1] = *(const bf16x8*)(sm + bb + aRow + (4 + m) * 2048 + kx1);
    }
  }
}

template<int QUAD>
__device__ __forceinline__ void qmfma(f32x4 acc[8][4], Frags& fr)
{
  constexpr int mo = (QUAD >= 2) ? 4 : 0;
  constexpr int no = (QUAD == 1 || QUAD == 2) ? 2 : 0;
  __builtin_amdgcn_s_setprio(1);
#pragma unroll
  for (int m = 0; m < 4; ++m)
#pragma unroll
    for (int n = 0; n < 2; ++n)
#pragma unroll
      for (int ks = 0; ks < 2; ++ks) {
        const bf16x8 bv = (no == 0) ? fr.b0F[n][ks] : fr.b1F[n][ks];
        acc[mo + m][no + n] =
            __builtin_amdgcn_mfma_f32_16x16x32_bf16(fr.aF[m][ks], bv, acc[mo + m][no + n], 0, 0, 0);
      }
  __builtin_amdgcn_s_setprio(0);
  __builtin_amdgcn_sched_barrier(0);
}

__global__ __launch_bounds__(512, 2)
void gemm256_nt(const unsigned short* __restrict__ A,
                const unsigned short* __restrict__ B,
                unsigned short* __restrict__ C,
                const float* __restrict__ bias,
                int K, long lda, long ldb, long ldc, int MT)
{
  __shared__ __align__(16) char sm[131072];

  const int nwg = gridDim.x;
  const int swz = (blockIdx.x & 7) * (nwg >> 3) + (blockIdx.x >> 3);
  const int mt = swz % MT, nt = swz / MT;

  const unsigned short* Ablk = A + (long)mt * 256 * lda;
  const unsigned short* Bblk = B + (long)nt * 256 * ldb;

  const int tid  = threadIdx.x;
  const int lane = tid & 63;
  const int w    = tid >> 6;
  const int wr   = w >> 2, wc = w & 3;

  const int rA  = tid >> 3;
  const int cSw = (tid ^ (tid >> 3)) & 7;

  const int aRow = wr * 16384 + (lane & 15) * 128;
  const int bRow = 32768 + (wc >> 1) * 16384 + ((wc & 1) * 64 + (lane & 15)) * 128;
  const int kq = (lane >> 4) * 16, sw = (lane & 7) << 4;
  const int kx0 = kq ^ sw;
  const int kx1 = (64 + kq) ^ sw;

  const int NT = K >> 6;
  const int NIT = NT >> 1;

  f32x4 acc[8][4] = {};
  Frags fr;

  auto stageA = [&](int half, int kt, int region) {
    const unsigned short* g = Ablk + ((long)(half * 128) + rA) * lda + (long)kt * 64 + cSw * 8;
    gload16(g,            sm + region + tid * 16);
    gload16(g + 64 * lda, sm + region + 8192 + tid * 16);
  };
  auto stageB = [&](int half, int kt, int region) {
    const unsigned short* g = Bblk + ((long)(half * 128) + rA) * ldb + (long)kt * 64 + cSw * 8;
    gload16(g,            sm + region + tid * 16);
    gload16(g + 64 * ldb, sm + region + 8192 + tid * 16);
  };

  stageA(0, 0, 0);
  stageA(1, 0, 16384);
  stageB(0, 0, 32768);
  stageB(1, 0, 49152);
  stageB(0, 1, 65536 + 32768);
  stageB(1, 1, 65536 + 49152);
  VMC4();
  SBAR();

#pragma unroll 1
  for (int it = 0; it < NIT; ++it) {
    const int kt1 = 2 * it + 1;
    const int kt2a = 2 * it + 2, kt2 = kt2a < NT ? kt2a : NT - 1;
    const int kt3a = 2 * it + 3, kt3 = kt3a < NT ? kt3a : NT - 1;

    qreads<0>(sm, 0, aRow, bRow, kx0, kx1, fr);
    stageA(0, kt1, 65536);
    SBAR(); LGKM0(); qmfma<0>(acc, fr); SBAR();

    qreads<1>(sm, 0, aRow, bRow, kx0, kx1, fr);
    stageA(1, kt1, 65536 + 16384);
    SBAR(); LGKM0(); qmfma<1>(acc, fr); SBAR();

    qreads<2>(sm, 0, aRow, bRow, kx0, kx1, fr);
    stageB(0, kt2, 32768);
    SBAR(); LGKM0(); qmfma<2>(acc, fr); SBAR();

    stageB(1, kt2, 49152);
    SBAR(); LGKM0(); qmfma<3>(acc, fr);
    VMC4();
    SBAR();

    qreads<0>(sm, 65536, aRow, bRow, kx0, kx1, fr);
    stageA(0, kt2, 0);
    SBAR(); LGKM0(); qmfma<0>(acc, fr); SBAR();

    qreads<1>(sm, 65536, aRow, bRow, kx0, kx1, fr);
    stageA(1, kt2, 16384);
    SBAR(); LGKM0(); qmfma<1>(acc, fr); SBAR();

    qreads<2>(sm, 65536, aRow, bRow, kx0, kx1, fr);
    stageB(0, kt3, 65536 + 32768);
    SBAR(); LGKM0(); qmfma<2>(acc, fr); SBAR();

    stageB(1, kt3, 65536 + 49152);
    SBAR(); LGKM0(); qmfma<3>(acc, fr);
    VMC4();
    SBAR();
  }

  const long crow0 = (long)mt * 256 + wr * 128;
  const long ccol0 = (long)nt * 256 + wc * 64;
#pragma unroll
  for (int m = 0; m < 8; ++m)
#pragma unroll
    for (int n = 0; n < 4; ++n) {
      const long col = ccol0 + n * 16 + (lane & 15);
      const float badd = bias[col];
#pragma unroll
      for (int j = 0; j < 4; ++j) {
        const long row = crow0 + m * 16 + (lane >> 4) * 4 + j;
        C[row * ldc + col] = f2bf(acc[m][n][j] + badd);
      }
    }
}

// ================= 128x128 NT GEMM, batched with h/b split ====================
// z = blockIdx.z; h = z/nb, b = z%nb; per-term element offsets.
// CMODE: 0 = fp32 store, 1 = bf16 store
template<int CMODE, int HAS_BIAS>
__global__ __launch_bounds__(256, 2)
void gemm_nt(const unsigned short* __restrict__ A,
             const unsigned short* __restrict__ B,
             void* __restrict__ C,
             const float* __restrict__ bias,
             float alpha, int K,
             long lda, long ldb, long ldc,
             long offA_h, long offA_b,
             long offB_h, long offB_b,
             long offC_h, long offC_b,
             long offBias_h, int nb)
{
  __shared__ __align__(16) unsigned short As[128 * 32];
  __shared__ __align__(16) unsigned short Bs[128 * 32];

  const int z = blockIdx.z;
  const int h = z / nb, bb = z - h * nb;
  const unsigned short* Ab = A + h * offA_h + bb * offA_b + (long)blockIdx.x * 128 * lda;
  const unsigned short* Bb = B + h * offB_h + bb * offB_b + (long)blockIdx.y * 128 * ldb;

  const int tid  = threadIdx.x;
  const int lane = tid & 63;
  const int w    = tid >> 6;
  const int wr   = w >> 1, wc = w & 1;

  const int c0 = tid, c1 = tid + 256;
  const int r0 = c0 >> 2, q0 = (c0 & 3) * 8;
  const int r1 = c1 >> 2, q1 = (c1 & 3) * 8;
  const unsigned short* gA0 = Ab + (long)r0 * lda + q0;
  const unsigned short* gA1 = Ab + (long)r1 * lda + q1;
  const unsigned short* gB0 = Bb + (long)r0 * ldb + q0;
  const unsigned short* gB1 = Bb + (long)r1 * ldb + q1;

  f32x4 acc[4][4] = {};

  const int arow = wr * 64 + (lane & 15);
  const int brow = wc * 64 + (lane & 15);
  const int kof  = (lane >> 4) * 8;

  for (int kt = 0; kt < K; kt += 32) {
    gload16(gA0, As + c0 * 8);
    gload16(gA1, As + c1 * 8);
    gload16(gB0, Bs + c0 * 8);
    gload16(gB1, Bs + c1 * 8);
    gA0 += 32; gA1 += 32; gB0 += 32; gB1 += 32;
    __syncthreads();

    bf16x8 af[4], bg[4];
#pragma unroll
    for (int m = 0; m < 4; ++m)
      af[m] = *(const bf16x8*)(As + (arow + m * 16) * 32 + kof);
#pragma unroll
    for (int n = 0; n < 4; ++n)
      bg[n] = *(const bf16x8*)(Bs + (brow + n * 16) * 32 + kof);

#pragma unroll
    for (int m = 0; m < 4; ++m)
#pragma unroll
      for (int n = 0; n < 4; ++n)
        acc[m][n] = __builtin_amdgcn_mfma_f32_16x16x32_bf16(af[m], bg[n], acc[m][n], 0, 0, 0);
    __syncthreads();
  }

  const long crow0 = (long)blockIdx.x * 128 + wr * 64;
  const long ccol0 = (long)blockIdx.y * 128 + wc * 64;
  const long cbase = h * offC_h + bb * offC_b;
  const float* biasb = HAS_BIAS ? (bias + h * offBias_h) : nullptr;

#pragma unroll
  for (int m = 0; m < 4; ++m) {
#pragma unroll
    for (int n = 0; n < 4; ++n) {
      const long col = ccol0 + n * 16 + (lane & 15);
      const float badd = HAS_BIAS ? biasb[col] : 0.0f;
#pragma unroll
      for (int j = 0; j < 4; ++j) {
        const long row = crow0 + m * 16 + (lane >> 4) * 4 + j;
        const float v = acc[m][n][j] * alpha + badd;
        const long idx = cbase + row * ldc + col;
        if (CMODE == 1) ((unsigned short*)C)[idx] = f2bf(v);
        else            ((float*)C)[idx] = v;
      }
    }
  }
}

// ---------------- softmax over rows of 1024 (fp32 in, bf16 out) ---------------
__global__ __launch_bounds__(256)
void softmax_k(const float* __restrict__ SC, unsigned short* __restrict__ P)
{
  const long row = blockIdx.x;
  const float* s = SC + (row << 10);
  unsigned short* p = P + (row << 10);
  const int tid = threadIdx.x;

  float4 v = ((const float4*)s)[tid];
  float mx = fmaxf(fmaxf(v.x, v.y), fmaxf(v.z, v.w));
#pragma unroll
  for (int o = 32; o >= 1; o >>= 1) mx = fmaxf(mx, __shfl_xor(mx, o));
  __shared__ float red[8];
  const int w = tid >> 6, lane = tid & 63;
  if (lane == 0) red[w] = mx;
  __syncthreads();
  mx = fmaxf(fmaxf(red[0], red[1]), fmaxf(red[2], red[3]));

  float e0 = __expf(v.x - mx), e1 = __expf(v.y - mx);
  float e2 = __expf(v.z - mx), e3 = __expf(v.w - mx);
  float sum = e0 + e1 + e2 + e3;
#pragma unroll
  for (int o = 32; o >= 1; o >>= 1) sum += __shfl_xor(sum, o);
  if (lane == 0) red[4 + w] = sum;
  __syncthreads();
  sum = red[4] + red[5] + red[6] + red[7];
  const float inv = 1.0f / sum;

  ushort4 o4;
  o4.x = f2bf(e0 * inv); o4.y = f2bf(e1 * inv);
  o4.z = f2bf(e2 * inv); o4.w = f2bf(e3 * inv);
  ((ushort4*)p)[tid] = o4;
}

// ---- V transpose: VT[z][e][t] = src[h*hStr + b*bStr + t*tStr + e], z=h*8+b ---
__global__ __launch_bounds__(256)
void transpose_v(const unsigned short* __restrict__ src, unsigned short* __restrict__ VT,
                 long tStr, long hStr, long bStr)
{
  const int z = blockIdx.z;
  const int hh = z >> 3, b = z & 7;
  const unsigned short* s = src + hh * hStr + b * bStr;
  __shared__ unsigned short tile[32][33];
  const int t0 = blockIdx.x * 32, e0 = blockIdx.y * 32;
  const int tx = threadIdx.x & 31, ty = threadIdx.x >> 5;
#pragma unroll
  for (int i = 0; i < 4; ++i) {
    const int tr = ty + i * 8;
    tile[tr][tx] = s[(long)(t0 + tr) * tStr + e0 + tx];
  }
  __syncthreads();
#pragma unroll
  for (int i = 0; i < 4; ++i) {
    const int er = ty + i * 8;
    VT[(long)z * 1048576 + (long)(e0 + er) * 1024 + t0 + tx] = tile[tx][er];
  }
}

// ---------------- converters --------------------------------------------------
__global__ __launch_bounds__(256)
void conv_bf16(const float* __restrict__ in, unsigned short* __restrict__ out, long n4)
{
  const long i = (long)blockIdx.x * 256 + threadIdx.x;
  if (i >= n4) return;
  const float4 v = ((const float4*)in)[i];
  ushort4 o; o.x = f2bf(v.x); o.y = f2bf(v.y); o.z = f2bf(v.z); o.w = f2bf(v.w);
  ((ushort4*)out)[i] = o;
}

// w_out [h][f][e] -> Wob[f][h*1024+e]
__global__ __launch_bounds__(256)
void conv_wout(const float* __restrict__ in, unsigned short* __restrict__ out)
{
  const long i = (long)blockIdx.x * 256 + threadIdx.x;   // 2M float4s
  const long o = i << 2;
  const long f = o >> 13, r = o & 8191;
  const long h = r >> 10, e = r & 1023;
  const float4 v = *(const float4*)(in + h * 1048576 + f * 1024 + e);
  ushort4 u; u.x = f2bf(v.x); u.y = f2bf(v.y); u.z = f2bf(v.z); u.w = f2bf(v.w);
  *(ushort4*)(out + o) = u;
}

__global__ __launch_bounds__(256)
void bias_sum_k(const float* __restrict__ b_out, float* __restrict__ bsum)
{
  const int f = blockIdx.x * 256 + threadIdx.x;
  if (f < 1024) {
    float s = 0.f;
#pragma unroll
    for (int h = 0; h < 8; ++h) s += b_out[h * 1024 + f];
    bsum[f] = s;
  }
}

// ---------------- launch ------------------------------------------------------
extern "C" void kernel_launch(void* const* d_in, const int* in_sizes, int n_in,
                              void* d_out, int out_size, void* d_ws, size_t ws_size,
                              hipStream_t stream)
{
  const float* x     = (const float*)d_in[0];
  const float* w_in  = (const float*)d_in[1];
  const float* b_in  = (const float*)d_in[2];
  const float* w_out = (const float*)d_in[3];
  const float* b_out = (const float*)d_in[4];
  float* out = (float*)d_out;

  char* ws = (char*)d_ws;
  const long MB = 1ll << 20;
  unsigned short* Xb   = (unsigned short*)(ws);              // 16 MiB
  unsigned short* Wob  = (unsigned short*)(ws + 16 * MB);    // 16 MiB
  float*          bsum = (float*)         (ws + 32 * MB);    // 4 KiB
  unsigned short* Ocat = (unsigned short*)(ws + 33 * MB);    // 128 MiB
  unsigned short* Wbg  = (unsigned short*)(ws + 161 * MB);   // 12 MiB
  unsigned short* QKVg = (unsigned short*)(ws + 173 * MB);   // 96 MiB
  float*          SCg  = (float*)         (ws + 269 * MB);   // 64 MiB
  unsigned short* Pg   = (unsigned short*)(ws + 333 * MB);   // 32 MiB -> 365 MiB
  unsigned short* VT   = (unsigned short*)SCg;               // alias (SC dead post-softmax)

  dim3 blk(256);

  conv_bf16 <<<8192, blk, 0, stream>>>(x, Xb, 2097152);
  conv_wout <<<8192, blk, 0, stream>>>(w_out, Wob);
  bias_sum_k<<<4,    blk, 0, stream>>>(b_out, bsum);

  for (int g = 0; g < 4; ++g) {
    // weights for heads 2g, 2g+1: [6144][1024] bf16
    conv_bf16<<<6144, blk, 0, stream>>>(w_in + (long)g * 6291456, Wbg, 1572864);

    // QKVg[sb][hh*3072 + sec*1024 + e] = Xb @ Wbg^T + b_in[g-rows]
    gemm256_nt<<<768, dim3(512), 0, stream>>>(
        Xb, Wbg, QKVg, b_in + (long)g * 6144, 1024, 1024, 1024, 6144, 32);

    // scores: z = hh*8 + b: SCg[z][s][t] = (Q K^T)/32, fp32
    gemm_nt<0,0><<<dim3(8, 8, 16), blk, 0, stream>>>(
        QKVg, QKVg + 1024, SCg, nullptr, 0.03125f, 1024,
        49152, 49152, 1024,  3072, 6144,  3072, 6144,  8388608, 1048576,  0, 8);

    softmax_k<<<16384, blk, 0, stream>>>(SCg, Pg);

    // VT[z][e][t] = V[(t*8+b)*6144 + hh*3072 + 2048 + e]
    transpose_v<<<dim3(32, 32, 16), blk, 0, stream>>>(
        QKVg + 2048, VT, 49152, 3072, 6144);

    // PV: Ocat[(s*8+b)*8192 + (2g+hh)*1024 + e] = sum_t P[z][s][t] VT[z][e][t]
    // s-stride in Ocat is 8*8192 = 65536 (rows are sb-major) -> ldc=65536.
    gemm_nt<1,0><<<dim3(8, 8, 16), blk, 0, stream>>>(
        Pg, VT, Ocat + (long)g * 2048, nullptr, 1.0f, 1024,
        1024, 1024, 65536,  8388608, 1048576,  8388608, 1048576,  1024, 8192,  0, 8);
  }

  // out = Ocat @ Wob^T + bsum   (8192 x 1024 x K=8192, fp32 out)
  gemm_nt<0,1><<<dim3(64, 8, 1), blk, 0, stream>>>(
      Ocat, Wob, out, bsum, 1.0f, 8192,
      8192, 8192, 1024,  0, 0,  0, 0,  0, 0,  0, 1);
}

// Round 6
// 1047.957 us; speedup vs baseline: 1.5910x; 1.2397x over previous
//
#include <hip/hip_runtime.h>
#include <hip/hip_bf16.h>

// MultiAttention: S=1024, B=8, D=1024, H=8
// Round 6: ALL GEMMs on the 256^2 8-phase engine (T2 swizzle + counted vmcnt +
// setprio), generalized with (h,b)-batch offsets and fp32/bf16 epilogues.
//   QKV:    per 2-head group, M8192 N6144 K1024 (768 blocks)
//   scores: per group, z=16 batched 1024^3 fp32 (256 blocks, 1/CU)
//   PV:     per group, z=16 batched 1024^3 bf16 scatter (256 blocks)
//   outproj: K-split z=2 (K=4096 each, 256 blocks) fp32 partials + add pass
// ws peak 365 MiB.

typedef __attribute__((ext_vector_type(8))) __bf16 bf16x8;
typedef __attribute__((ext_vector_type(4))) float f32x4;

__device__ __forceinline__ unsigned short f2bf(float f) {
  union { float f; unsigned u; } x; x.f = f;
  unsigned r = x.u + 0x7fffu + ((x.u >> 16) & 1u);   // RNE
  return (unsigned short)(r >> 16);
}

__device__ __forceinline__ void gload16(const void* g, void* l) {
  __builtin_amdgcn_global_load_lds(
      (const __attribute__((address_space(1))) void*)g,
      (__attribute__((address_space(3))) void*)l, 16, 0, 0);
}

#define SBAR()  do { __builtin_amdgcn_sched_barrier(0); __builtin_amdgcn_s_barrier(); \
                     __builtin_amdgcn_sched_barrier(0); } while (0)
#define LGKM0() do { asm volatile("s_waitcnt lgkmcnt(0)" ::: "memory"); \
                     __builtin_amdgcn_sched_barrier(0); } while (0)
#define VMC4()  do { asm volatile("s_waitcnt vmcnt(4)" ::: "memory"); \
                     __builtin_amdgcn_sched_barrier(0); } while (0)

// ================= 256x256 8-phase NT GEMM ====================================
// C = alpha*(A @ B^T) [+bias[col]].  Batched: z = swz/(MT*NTt), h=z/nb, b=z%nb.
// K % 128 == 0. grid.x = MT*NTt*nz (multiple of 8). 512 threads, LDS 128 KiB.
struct Frags { bf16x8 aF[4][2]; bf16x8 b0F[2][2]; bf16x8 b1F[2][2]; };

template<int QUAD>
__device__ __forceinline__ void qreads(const char* sm, int bb, int aRow, int bRow,
                                       int kx0, int kx1, Frags& fr)
{
  if constexpr (QUAD == 0) {
#pragma unroll
    for (int m = 0; m < 4; ++m) {
      fr.aF[m][0] = *(const bf16x8*)(sm + bb + aRow + m * 2048 + kx0);
      fr.aF[m][1] = *(const bf16x8*)(sm + bb + aRow + m * 2048 + kx1);
    }
#pragma unroll
    for (int n = 0; n < 2; ++n) {
      fr.b0F[n][0] = *(const bf16x8*)(sm + bb + bRow + n * 2048 + kx0);
      fr.b0F[n][1] = *(const bf16x8*)(sm + bb + bRow + n * 2048 + kx1);
    }
  } else if constexpr (QUAD == 1) {
#pragma unroll
    for (int n = 0; n < 2; ++n) {
      fr.b1F[n][0] = *(const bf16x8*)(sm + bb + bRow + (2 + n) * 2048 + kx0);
      fr.b1F[n][1] = *(const bf16x8*)(sm + bb + bRow + (2 + n) * 2048 + kx1);
    }
  } else if constexpr (QUAD == 2) {
#pragma unroll
    for (int m = 0; m < 4; ++m) {
      fr.aF[m][0] = *(const bf16x8*)(sm + bb + aRow + (4 + m) * 2048 + kx0);
      fr.aF[m][1] = *(const bf16x8*)(sm + bb + aRow + (4 + m) * 2048 + kx1);
    }
  }
}

template<int QUAD>
__device__ __forceinline__ void qmfma(f32x4 acc[8][4], Frags& fr)
{
  constexpr int mo = (QUAD >= 2) ? 4 : 0;
  constexpr int no = (QUAD == 1 || QUAD == 2) ? 2 : 0;
  __builtin_amdgcn_s_setprio(1);
#pragma unroll
  for (int m = 0; m < 4; ++m)
#pragma unroll
    for (int n = 0; n < 2; ++n)
#pragma unroll
      for (int ks = 0; ks < 2; ++ks) {
        const bf16x8 bv = (no == 0) ? fr.b0F[n][ks] : fr.b1F[n][ks];
        acc[mo + m][no + n] =
            __builtin_amdgcn_mfma_f32_16x16x32_bf16(fr.aF[m][ks], bv, acc[mo + m][no + n], 0, 0, 0);
      }
  __builtin_amdgcn_s_setprio(0);
  __builtin_amdgcn_sched_barrier(0);
}

template<int OUT_BF16, int HAS_BIAS, int NT_FAST>
__global__ __launch_bounds__(512, 2)
void gemm256_nt(const unsigned short* __restrict__ A,
                const unsigned short* __restrict__ B,
                void* __restrict__ C,
                const float* __restrict__ bias,
                float alpha, int K,
                long lda, long ldb, long ldc,
                long offA_h, long offA_b,
                long offB_h, long offB_b,
                long offC_h, long offC_b,
                int MT, int NTt, int nb)
{
  __shared__ __align__(16) char sm[131072];

  const int nwg = gridDim.x;
  const int swz = (blockIdx.x & 7) * (nwg >> 3) + (blockIdx.x >> 3);
  const int per_z = MT * NTt;
  const int z = swz / per_z;
  const int r = swz - z * per_z;
  const int mt = NT_FAST ? (r / NTt) : (r % MT);
  const int nt = NT_FAST ? (r % NTt) : (r / MT);
  const int h = z / nb, bz = z - h * nb;

  const unsigned short* Ablk = A + h * offA_h + bz * offA_b + (long)mt * 256 * lda;
  const unsigned short* Bblk = B + h * offB_h + bz * offB_b + (long)nt * 256 * ldb;

  const int tid  = threadIdx.x;
  const int lane = tid & 63;
  const int w    = tid >> 6;
  const int wr   = w >> 2, wc = w & 3;

  const int rA  = tid >> 3;
  const int cSw = (tid ^ (tid >> 3)) & 7;

  const int aRow = wr * 16384 + (lane & 15) * 128;
  const int bRow = 32768 + (wc >> 1) * 16384 + ((wc & 1) * 64 + (lane & 15)) * 128;
  const int kq = (lane >> 4) * 16, sw = (lane & 7) << 4;
  const int kx0 = kq ^ sw;
  const int kx1 = (64 + kq) ^ sw;

  const int NT = K >> 6;
  const int NIT = NT >> 1;

  f32x4 acc[8][4] = {};
  Frags fr;

  auto stageA = [&](int half, int kt, int region) {
    const unsigned short* g = Ablk + ((long)(half * 128) + rA) * lda + (long)kt * 64 + cSw * 8;
    gload16(g,            sm + region + tid * 16);
    gload16(g + 64 * lda, sm + region + 8192 + tid * 16);
  };
  auto stageB = [&](int half, int kt, int region) {
    const unsigned short* g = Bblk + ((long)(half * 128) + rA) * ldb + (long)kt * 64 + cSw * 8;
    gload16(g,            sm + region + tid * 16);
    gload16(g + 64 * ldb, sm + region + 8192 + tid * 16);
  };

  stageA(0, 0, 0);
  stageA(1, 0, 16384);
  stageB(0, 0, 32768);
  stageB(1, 0, 49152);
  stageB(0, 1, 65536 + 32768);
  stageB(1, 1, 65536 + 49152);
  VMC4();
  SBAR();

#pragma unroll 1
  for (int it = 0; it < NIT; ++it) {
    const int kt1 = 2 * it + 1;
    const int kt2a = 2 * it + 2, kt2 = kt2a < NT ? kt2a : NT - 1;
    const int kt3a = 2 * it + 3, kt3 = kt3a < NT ? kt3a : NT - 1;

    qreads<0>(sm, 0, aRow, bRow, kx0, kx1, fr);
    stageA(0, kt1, 65536);
    SBAR(); LGKM0(); qmfma<0>(acc, fr); SBAR();

    qreads<1>(sm, 0, aRow, bRow, kx0, kx1, fr);
    stageA(1, kt1, 65536 + 16384);
    SBAR(); LGKM0(); qmfma<1>(acc, fr); SBAR();

    qreads<2>(sm, 0, aRow, bRow, kx0, kx1, fr);
    stageB(0, kt2, 32768);
    SBAR(); LGKM0(); qmfma<2>(acc, fr); SBAR();

    stageB(1, kt2, 49152);
    SBAR(); LGKM0(); qmfma<3>(acc, fr);
    VMC4();
    SBAR();

    qreads<0>(sm, 65536, aRow, bRow, kx0, kx1, fr);
    stageA(0, kt2, 0);
    SBAR(); LGKM0(); qmfma<0>(acc, fr); SBAR();

    qreads<1>(sm, 65536, aRow, bRow, kx0, kx1, fr);
    stageA(1, kt2, 16384);
    SBAR(); LGKM0(); qmfma<1>(acc, fr); SBAR();

    qreads<2>(sm, 65536, aRow, bRow, kx0, kx1, fr);
    stageB(0, kt3, 65536 + 32768);
    SBAR(); LGKM0(); qmfma<2>(acc, fr); SBAR();

    stageB(1, kt3, 65536 + 49152);
    SBAR(); LGKM0(); qmfma<3>(acc, fr);
    VMC4();
    SBAR();
  }

  // epilogue: C/D layout col = lane&15, row = (lane>>4)*4 + j
  const long crow0 = (long)mt * 256 + wr * 128;
  const long ccol0 = (long)nt * 256 + wc * 64;
  const long cbase = h * offC_h + bz * offC_b;
#pragma unroll
  for (int m = 0; m < 8; ++m)
#pragma unroll
    for (int n = 0; n < 4; ++n) {
      const long col = ccol0 + n * 16 + (lane & 15);
      const float badd = HAS_BIAS ? bias[col] : 0.0f;
#pragma unroll
      for (int j = 0; j < 4; ++j) {
        const long row = crow0 + m * 16 + (lane >> 4) * 4 + j;
        const float v = acc[m][n][j] * alpha + badd;
        const long idx = cbase + row * ldc + col;
        if (OUT_BF16) ((unsigned short*)C)[idx] = f2bf(v);
        else          ((float*)C)[idx] = v;
      }
    }
}

// ---------------- softmax over rows of 1024 (fp32 in, bf16 out) ---------------
__global__ __launch_bounds__(256)
void softmax_k(const float* __restrict__ SC, unsigned short* __restrict__ P)
{
  const long row = blockIdx.x;
  const float* s = SC + (row << 10);
  unsigned short* p = P + (row << 10);
  const int tid = threadIdx.x;

  float4 v = ((const float4*)s)[tid];
  float mx = fmaxf(fmaxf(v.x, v.y), fmaxf(v.z, v.w));
#pragma unroll
  for (int o = 32; o >= 1; o >>= 1) mx = fmaxf(mx, __shfl_xor(mx, o));
  __shared__ float red[8];
  const int w = tid >> 6, lane = tid & 63;
  if (lane == 0) red[w] = mx;
  __syncthreads();
  mx = fmaxf(fmaxf(red[0], red[1]), fmaxf(red[2], red[3]));

  float e0 = __expf(v.x - mx), e1 = __expf(v.y - mx);
  float e2 = __expf(v.z - mx), e3 = __expf(v.w - mx);
  float sum = e0 + e1 + e2 + e3;
#pragma unroll
  for (int o = 32; o >= 1; o >>= 1) sum += __shfl_xor(sum, o);
  if (lane == 0) red[4 + w] = sum;
  __syncthreads();
  sum = red[4] + red[5] + red[6] + red[7];
  const float inv = 1.0f / sum;

  ushort4 o4;
  o4.x = f2bf(e0 * inv); o4.y = f2bf(e1 * inv);
  o4.z = f2bf(e2 * inv); o4.w = f2bf(e3 * inv);
  ((ushort4*)p)[tid] = o4;
}

// ---- V transpose: VT[z][e][t] = src[h*hStr + b*bStr + t*tStr + e], z=h*8+b ---
__global__ __launch_bounds__(256)
void transpose_v(const unsigned short* __restrict__ src, unsigned short* __restrict__ VT,
                 long tStr, long hStr, long bStr)
{
  const int z = blockIdx.z;
  const int hh = z >> 3, b = z & 7;
  const unsigned short* s = src + hh * hStr + b * bStr;
  __shared__ unsigned short tile[32][33];
  const int t0 = blockIdx.x * 32, e0 = blockIdx.y * 32;
  const int tx = threadIdx.x & 31, ty = threadIdx.x >> 5;
#pragma unroll
  for (int i = 0; i < 4; ++i) {
    const int tr = ty + i * 8;
    tile[tr][tx] = s[(long)(t0 + tr) * tStr + e0 + tx];
  }
  __syncthreads();
#pragma unroll
  for (int i = 0; i < 4; ++i) {
    const int er = ty + i * 8;
    VT[(long)z * 1048576 + (long)(e0 + er) * 1024 + t0 + tx] = tile[tx][er];
  }
}

// ---------------- converters / epilogue add -----------------------------------
__global__ __launch_bounds__(256)
void conv_bf16(const float* __restrict__ in, unsigned short* __restrict__ out, long n4)
{
  const long i = (long)blockIdx.x * 256 + threadIdx.x;
  if (i >= n4) return;
  const float4 v = ((const float4*)in)[i];
  ushort4 o; o.x = f2bf(v.x); o.y = f2bf(v.y); o.z = f2bf(v.z); o.w = f2bf(v.w);
  ((ushort4*)out)[i] = o;
}

// w_out [h][f][e] -> Wob[f][h*1024+e]
__global__ __launch_bounds__(256)
void conv_wout(const float* __restrict__ in, unsigned short* __restrict__ out)
{
  const long i = (long)blockIdx.x * 256 + threadIdx.x;   // 2M float4s
  const long o = i << 2;
  const long f = o >> 13, r = o & 8191;
  const long h = r >> 10, e = r & 1023;
  const float4 v = *(const float4*)(in + h * 1048576 + f * 1024 + e);
  ushort4 u; u.x = f2bf(v.x); u.y = f2bf(v.y); u.z = f2bf(v.z); u.w = f2bf(v.w);
  *(ushort4*)(out + o) = u;
}

__global__ __launch_bounds__(256)
void bias_sum_k(const float* __restrict__ b_out, float* __restrict__ bsum)
{
  const int f = blockIdx.x * 256 + threadIdx.x;
  if (f < 1024) {
    float s = 0.f;
#pragma unroll
    for (int h = 0; h < 8; ++h) s += b_out[h * 1024 + f];
    bsum[f] = s;
  }
}

// out = p[0] + p[1] + bsum   (2M float4)
__global__ __launch_bounds__(256)
void add_out_k(const float* __restrict__ p, float* __restrict__ out,
               const float* __restrict__ bsum)
{
  const long i = (long)blockIdx.x * 256 + threadIdx.x;
  const float4 a = ((const float4*)p)[i];
  const float4 b = ((const float4*)(p + 8388608))[i];
  const float4 s = ((const float4*)bsum)[i & 255];
  float4 o;
  o.x = a.x + b.x + s.x; o.y = a.y + b.y + s.y;
  o.z = a.z + b.z + s.z; o.w = a.w + b.w + s.w;
  ((float4*)out)[i] = o;
}

// ---------------- launch ------------------------------------------------------
extern "C" void kernel_launch(void* const* d_in, const int* in_sizes, int n_in,
                              void* d_out, int out_size, void* d_ws, size_t ws_size,
                              hipStream_t stream)
{
  const float* x     = (const float*)d_in[0];
  const float* w_in  = (const float*)d_in[1];
  const float* b_in  = (const float*)d_in[2];
  const float* w_out = (const float*)d_in[3];
  const float* b_out = (const float*)d_in[4];
  float* out = (float*)d_out;

  char* ws = (char*)d_ws;
  const long MB = 1ll << 20;
  unsigned short* Xb   = (unsigned short*)(ws);              // 16 MiB
  unsigned short* Wob  = (unsigned short*)(ws + 16 * MB);    // 16 MiB
  float*          bsum = (float*)         (ws + 32 * MB);    // 4 KiB
  unsigned short* Ocat = (unsigned short*)(ws + 33 * MB);    // 128 MiB
  unsigned short* Wbg  = (unsigned short*)(ws + 161 * MB);   // 12 MiB
  unsigned short* QKVg = (unsigned short*)(ws + 173 * MB);   // 96 MiB
  float*          SCg  = (float*)         (ws + 269 * MB);   // 64 MiB
  unsigned short* Pg   = (unsigned short*)(ws + 333 * MB);   // 32 MiB -> 365 MiB
  unsigned short* VT   = (unsigned short*)SCg;               // alias (SC dead post-softmax)
  float*          Opart = (float*)        (ws + 269 * MB);   // 64 MiB alias (post-attention)

  dim3 blk(256), blk512(512);

  conv_bf16 <<<8192, blk, 0, stream>>>(x, Xb, 2097152);
  conv_wout <<<8192, blk, 0, stream>>>(w_out, Wob);
  bias_sum_k<<<4,    blk, 0, stream>>>(b_out, bsum);

  for (int g = 0; g < 4; ++g) {
    // weights for heads 2g, 2g+1: [6144][1024] bf16
    conv_bf16<<<6144, blk, 0, stream>>>(w_in + (long)g * 6291456, Wbg, 1572864);

    // QKVg[sb][hh*3072 + sec*1024 + e] = Xb @ Wbg^T + b_in[g-rows]
    gemm256_nt<1,1,0><<<768, blk512, 0, stream>>>(
        Xb, Wbg, QKVg, b_in + (long)g * 6144, 1.0f, 1024,
        1024, 1024, 6144,  0, 0,  0, 0,  0, 0,  32, 24, 1);

    // scores: z = hh*8+b: SCg[z][s][t] = (Q K^T)/32, fp32 (256 blocks, 1/CU)
    gemm256_nt<0,0,0><<<256, blk512, 0, stream>>>(
        QKVg, QKVg + 1024, SCg, nullptr, 0.03125f, 1024,
        49152, 49152, 1024,  3072, 6144,  3072, 6144,  8388608, 1048576,  4, 4, 8);

    softmax_k<<<16384, blk, 0, stream>>>(SCg, Pg);

    // VT[z][e][t] = V[(t*8+b)*6144 + hh*3072 + 2048 + e]
    transpose_v<<<dim3(32, 32, 16), blk, 0, stream>>>(
        QKVg + 2048, VT, 49152, 3072, 6144);

    // PV: Ocat[(s*8+b)*8192 + (2g+hh)*1024 + e] = sum_t P[z][s][t] VT[z][e][t]
    gemm256_nt<1,0,0><<<256, blk512, 0, stream>>>(
        Pg, VT, Ocat + (long)g * 2048, nullptr, 1.0f, 1024,
        1024, 1024, 65536,  8388608, 1048576,  8388608, 1048576,  1024, 8192,  4, 4, 8);
  }

  // outproj K-split: Opart[z] = Ocat[:, z*4096:(z+1)*4096] @ Wob[:, same]^T
  gemm256_nt<0,0,1><<<256, blk512, 0, stream>>>(
      Ocat, Wob, Opart, nullptr, 1.0f, 4096,
      8192, 8192, 1024,  0, 4096,  0, 4096,  0, 8388608,  32, 4, 2);

  add_out_k<<<8192, blk, 0, stream>>>(Opart, out, bsum);
}

// Round 7
// 1043.119 us; speedup vs baseline: 1.5984x; 1.0046x over previous
//
#include <hip/hip_runtime.h>
#include <hip/hip_bf16.h>

// MultiAttention: S=1024, B=8, D=1024, H=8
// Round 7: QKV becomes a PERSISTENT multi-tile 8-phase GEMM: 256 blocks, each
// runs 3 nt-tiles (48 K-tiles) through ONE continuous pipeline, dumping acc at
// 16-K-tile boundaries. Scores/PV/outproj unchanged from round 6 (isolated A/B).
// ws peak 365 MiB.

typedef __attribute__((ext_vector_type(8))) __bf16 bf16x8;
typedef __attribute__((ext_vector_type(4))) float f32x4;

__device__ __forceinline__ unsigned short f2bf(float f) {
  union { float f; unsigned u; } x; x.f = f;
  unsigned r = x.u + 0x7fffu + ((x.u >> 16) & 1u);   // RNE
  return (unsigned short)(r >> 16);
}

__device__ __forceinline__ void gload16(const void* g, void* l) {
  __builtin_amdgcn_global_load_lds(
      (const __attribute__((address_space(1))) void*)g,
      (__attribute__((address_space(3))) void*)l, 16, 0, 0);
}

#define SBAR()  do { __builtin_amdgcn_sched_barrier(0); __builtin_amdgcn_s_barrier(); \
                     __builtin_amdgcn_sched_barrier(0); } while (0)
#define LGKM0() do { asm volatile("s_waitcnt lgkmcnt(0)" ::: "memory"); \
                     __builtin_amdgcn_sched_barrier(0); } while (0)
#define VMC4()  do { asm volatile("s_waitcnt vmcnt(4)" ::: "memory"); \
                     __builtin_amdgcn_sched_barrier(0); } while (0)

// ================= shared 8-phase building blocks =============================
struct Frags { bf16x8 aF[4][2]; bf16x8 b0F[2][2]; bf16x8 b1F[2][2]; };

template<int QUAD>
__device__ __forceinline__ void qreads(const char* sm, int bb, int aRow, int bRow,
                                       int kx0, int kx1, Frags& fr)
{
  if constexpr (QUAD == 0) {
#pragma unroll
    for (int m = 0; m < 4; ++m) {
      fr.aF[m][0] = *(const bf16x8*)(sm + bb + aRow + m * 2048 + kx0);
      fr.aF[m][1] = *(const bf16x8*)(sm + bb + aRow + m * 2048 + kx1);
    }
#pragma unroll
    for (int n = 0; n < 2; ++n) {
      fr.b0F[n][0] = *(const bf16x8*)(sm + bb + bRow + n * 2048 + kx0);
      fr.b0F[n][1] = *(const bf16x8*)(sm + bb + bRow + n * 2048 + kx1);
    }
  } else if constexpr (QUAD == 1) {
#pragma unroll
    for (int n = 0; n < 2; ++n) {
      fr.b1F[n][0] = *(const bf16x8*)(sm + bb + bRow + (2 + n) * 2048 + kx0);
      fr.b1F[n][1] = *(const bf16x8*)(sm + bb + bRow + (2 + n) * 2048 + kx1);
    }
  } else if constexpr (QUAD == 2) {
#pragma unroll
    for (int m = 0; m < 4; ++m) {
      fr.aF[m][0] = *(const bf16x8*)(sm + bb + aRow + (4 + m) * 2048 + kx0);
      fr.aF[m][1] = *(const bf16x8*)(sm + bb + aRow + (4 + m) * 2048 + kx1);
    }
  }
}

template<int QUAD>
__device__ __forceinline__ void qmfma(f32x4 acc[8][4], Frags& fr)
{
  constexpr int mo = (QUAD >= 2) ? 4 : 0;
  constexpr int no = (QUAD == 1 || QUAD == 2) ? 2 : 0;
  __builtin_amdgcn_s_setprio(1);
#pragma unroll
  for (int m = 0; m < 4; ++m)
#pragma unroll
    for (int n = 0; n < 2; ++n)
#pragma unroll
      for (int ks = 0; ks < 2; ++ks) {
        const bf16x8 bv = (no == 0) ? fr.b0F[n][ks] : fr.b1F[n][ks];
        acc[mo + m][no + n] =
            __builtin_amdgcn_mfma_f32_16x16x32_bf16(fr.aF[m][ks], bv, acc[mo + m][no + n], 0, 0, 0);
      }
  __builtin_amdgcn_s_setprio(0);
  __builtin_amdgcn_sched_barrier(0);
}

// ============ persistent multi-tile QKV: A[8192][1024] @ B[6144][1024]^T ======
// 256 blocks (32 mt x 8 ntg); each block computes nt = ntg*3+tau, tau=0..2,
// through one continuous 48-K-tile pipeline. C[8192][6144] bf16 + bias.
__global__ __launch_bounds__(512, 2)
void gemm256_qkv(const unsigned short* __restrict__ A,
                 const unsigned short* __restrict__ B,
                 unsigned short* __restrict__ C,
                 const float* __restrict__ bias)
{
  __shared__ __align__(16) char sm[131072];
  const int mt  = blockIdx.x >> 3;     // 0..31
  const int ntg = blockIdx.x & 7;      // XCD chunk: shares 3 B-panels
  const int nt0 = ntg * 3;

  const unsigned short* Ablk = A + (long)mt * 256 * 1024;

  const int tid  = threadIdx.x;
  const int lane = tid & 63;
  const int w    = tid >> 6;
  const int wr   = w >> 2, wc = w & 3;

  const int rA  = tid >> 3;
  const int cSw = (tid ^ (tid >> 3)) & 7;

  const int aRow = wr * 16384 + (lane & 15) * 128;
  const int bRow = 32768 + (wc >> 1) * 16384 + ((wc & 1) * 64 + (lane & 15)) * 128;
  const int kq = (lane >> 4) * 16, sw = (lane & 7) << 4;
  const int kx0 = kq ^ sw;
  const int kx1 = (64 + kq) ^ sw;

  const int NTtot = 48;
  const int NIT   = 24;

  f32x4 acc[8][4] = {};
  Frags fr;

  auto stageA = [&](int half, int kt, int region) {
    const int kk = kt & 15;
    const unsigned short* g = Ablk + ((long)(half * 128) + rA) * 1024 + kk * 64 + cSw * 8;
    gload16(g,             sm + region + tid * 16);
    gload16(g + 64 * 1024, sm + region + 8192 + tid * 16);
  };
  auto stageB = [&](int half, int kt, int region) {
    const int tau = kt >> 4, kk = kt & 15;
    const unsigned short* g =
        B + ((long)((nt0 + tau) * 256 + half * 128) + rA) * 1024 + kk * 64 + cSw * 8;
    gload16(g,             sm + region + tid * 16);
    gload16(g + 64 * 1024, sm + region + 8192 + tid * 16);
  };

  stageA(0, 0, 0);
  stageA(1, 0, 16384);
  stageB(0, 0, 32768);
  stageB(1, 0, 49152);
  stageB(0, 1, 65536 + 32768);
  stageB(1, 1, 65536 + 49152);
  VMC4();
  SBAR();

#pragma unroll 1
  for (int it = 0; it < NIT; ++it) {
    const int kt1 = 2 * it + 1;
    const int kt2a = 2 * it + 2, kt2 = kt2a < NTtot ? kt2a : NTtot - 1;
    const int kt3a = 2 * it + 3, kt3 = kt3a < NTtot ? kt3a : NTtot - 1;

    qreads<0>(sm, 0, aRow, bRow, kx0, kx1, fr);
    stageA(0, kt1, 65536);
    SBAR(); LGKM0(); qmfma<0>(acc, fr); SBAR();

    qreads<1>(sm, 0, aRow, bRow, kx0, kx1, fr);
    stageA(1, kt1, 65536 + 16384);
    SBAR(); LGKM0(); qmfma<1>(acc, fr); SBAR();

    qreads<2>(sm, 0, aRow, bRow, kx0, kx1, fr);
    stageB(0, kt2, 32768);
    SBAR(); LGKM0(); qmfma<2>(acc, fr); SBAR();

    stageB(1, kt2, 49152);
    SBAR(); LGKM0(); qmfma<3>(acc, fr);
    VMC4();
    SBAR();

    qreads<0>(sm, 65536, aRow, bRow, kx0, kx1, fr);
    stageA(0, kt2, 0);
    SBAR(); LGKM0(); qmfma<0>(acc, fr); SBAR();

    qreads<1>(sm, 65536, aRow, bRow, kx0, kx1, fr);
    stageA(1, kt2, 16384);
    SBAR(); LGKM0(); qmfma<1>(acc, fr); SBAR();

    qreads<2>(sm, 65536, aRow, bRow, kx0, kx1, fr);
    stageB(0, kt3, 65536 + 32768);
    SBAR(); LGKM0(); qmfma<2>(acc, fr); SBAR();

    stageB(1, kt3, 65536 + 49152);
    SBAR(); LGKM0(); qmfma<3>(acc, fr);
    VMC4();
    SBAR();

    if ((it & 7) == 7) {   // tile boundary (fully-synced point): dump acc, reset
      const int nt = nt0 + (it >> 3);
      const long crow0 = (long)mt * 256 + wr * 128;
      const long ccol0 = (long)nt * 256 + wc * 64;
#pragma unroll
      for (int m = 0; m < 8; ++m)
#pragma unroll
        for (int n = 0; n < 4; ++n) {
          const long col = ccol0 + n * 16 + (lane & 15);
          const float badd = bias[col];
#pragma unroll
          for (int j = 0; j < 4; ++j) {
            const long row = crow0 + m * 16 + (lane >> 4) * 4 + j;
            C[row * 6144 + col] = f2bf(acc[m][n][j] + badd);
            acc[m][n][j] = 0.0f;
          }
        }
      __builtin_amdgcn_sched_barrier(0);
    }
  }
}

// ================= generic 256x256 8-phase NT GEMM (round-6, proven) ==========
template<int OUT_BF16, int HAS_BIAS, int NT_FAST>
__global__ __launch_bounds__(512, 2)
void gemm256_nt(const unsigned short* __restrict__ A,
                const unsigned short* __restrict__ B,
                void* __restrict__ C,
                const float* __restrict__ bias,
                float alpha, int K,
                long lda, long ldb, long ldc,
                long offA_h, long offA_b,
                long offB_h, long offB_b,
                long offC_h, long offC_b,
                int MT, int NTt, int nb)
{
  __shared__ __align__(16) char sm[131072];

  const int nwg = gridDim.x;
  const int swz = (blockIdx.x & 7) * (nwg >> 3) + (blockIdx.x >> 3);
  const int per_z = MT * NTt;
  const int z = swz / per_z;
  const int r = swz - z * per_z;
  const int mt = NT_FAST ? (r / NTt) : (r % MT);
  const int nt = NT_FAST ? (r % NTt) : (r / MT);
  const int h = z / nb, bz = z - h * nb;

  const unsigned short* Ablk = A + h * offA_h + bz * offA_b + (long)mt * 256 * lda;
  const unsigned short* Bblk = B + h * offB_h + bz * offB_b + (long)nt * 256 * ldb;

  const int tid  = threadIdx.x;
  const int lane = tid & 63;
  const int w    = tid >> 6;
  const int wr   = w >> 2, wc = w & 3;

  const int rA  = tid >> 3;
  const int cSw = (tid ^ (tid >> 3)) & 7;

  const int aRow = wr * 16384 + (lane & 15) * 128;
  const int bRow = 32768 + (wc >> 1) * 16384 + ((wc & 1) * 64 + (lane & 15)) * 128;
  const int kq = (lane >> 4) * 16, sw = (lane & 7) << 4;
  const int kx0 = kq ^ sw;
  const int kx1 = (64 + kq) ^ sw;

  const int NT = K >> 6;
  const int NIT = NT >> 1;

  f32x4 acc[8][4] = {};
  Frags fr;

  auto stageA = [&](int half, int kt, int region) {
    const unsigned short* g = Ablk + ((long)(half * 128) + rA) * lda + (long)kt * 64 + cSw * 8;
    gload16(g,            sm + region + tid * 16);
    gload16(g + 64 * lda, sm + region + 8192 + tid * 16);
  };
  auto stageB = [&](int half, int kt, int region) {
    const unsigned short* g = Bblk + ((long)(half * 128) + rA) * ldb + (long)kt * 64 + cSw * 8;
    gload16(g,            sm + region + tid * 16);
    gload16(g + 64 * ldb, sm + region + 8192 + tid * 16);
  };

  stageA(0, 0, 0);
  stageA(1, 0, 16384);
  stageB(0, 0, 32768);
  stageB(1, 0, 49152);
  stageB(0, 1, 65536 + 32768);
  stageB(1, 1, 65536 + 49152);
  VMC4();
  SBAR();

#pragma unroll 1
  for (int it = 0; it < NIT; ++it) {
    const int kt1 = 2 * it + 1;
    const int kt2a = 2 * it + 2, kt2 = kt2a < NT ? kt2a : NT - 1;
    const int kt3a = 2 * it + 3, kt3 = kt3a < NT ? kt3a : NT - 1;

    qreads<0>(sm, 0, aRow, bRow, kx0, kx1, fr);
    stageA(0, kt1, 65536);
    SBAR(); LGKM0(); qmfma<0>(acc, fr); SBAR();

    qreads<1>(sm, 0, aRow, bRow, kx0, kx1, fr);
    stageA(1, kt1, 65536 + 16384);
    SBAR(); LGKM0(); qmfma<1>(acc, fr); SBAR();

    qreads<2>(sm, 0, aRow, bRow, kx0, kx1, fr);
    stageB(0, kt2, 32768);
    SBAR(); LGKM0(); qmfma<2>(acc, fr); SBAR();

    stageB(1, kt2, 49152);
    SBAR(); LGKM0(); qmfma<3>(acc, fr);
    VMC4();
    SBAR();

    qreads<0>(sm, 65536, aRow, bRow, kx0, kx1, fr);
    stageA(0, kt2, 0);
    SBAR(); LGKM0(); qmfma<0>(acc, fr); SBAR();

    qreads<1>(sm, 65536, aRow, bRow, kx0, kx1, fr);
    stageA(1, kt2, 16384);
    SBAR(); LGKM0(); qmfma<1>(acc, fr); SBAR();

    qreads<2>(sm, 65536, aRow, bRow, kx0, kx1, fr);
    stageB(0, kt3, 65536 + 32768);
    SBAR(); LGKM0(); qmfma<2>(acc, fr); SBAR();

    stageB(1, kt3, 65536 + 49152);
    SBAR(); LGKM0(); qmfma<3>(acc, fr);
    VMC4();
    SBAR();
  }

  const long crow0 = (long)mt * 256 + wr * 128;
  const long ccol0 = (long)nt * 256 + wc * 64;
  const long cbase = h * offC_h + bz * offC_b;
#pragma unroll
  for (int m = 0; m < 8; ++m)
#pragma unroll
    for (int n = 0; n < 4; ++n) {
      const long col = ccol0 + n * 16 + (lane & 15);
      const float badd = HAS_BIAS ? bias[col] : 0.0f;
#pragma unroll
      for (int j = 0; j < 4; ++j) {
        const long row = crow0 + m * 16 + (lane >> 4) * 4 + j;
        const float v = acc[m][n][j] * alpha + badd;
        const long idx = cbase + row * ldc + col;
        if (OUT_BF16) ((unsigned short*)C)[idx] = f2bf(v);
        else          ((float*)C)[idx] = v;
      }
    }
}

// ---------------- softmax over rows of 1024 (fp32 in, bf16 out) ---------------
__global__ __launch_bounds__(256)
void softmax_k(const float* __restrict__ SC, unsigned short* __restrict__ P)
{
  const long row = blockIdx.x;
  const float* s = SC + (row << 10);
  unsigned short* p = P + (row << 10);
  const int tid = threadIdx.x;

  float4 v = ((const float4*)s)[tid];
  float mx = fmaxf(fmaxf(v.x, v.y), fmaxf(v.z, v.w));
#pragma unroll
  for (int o = 32; o >= 1; o >>= 1) mx = fmaxf(mx, __shfl_xor(mx, o));
  __shared__ float red[8];
  const int w = tid >> 6, lane = tid & 63;
  if (lane == 0) red[w] = mx;
  __syncthreads();
  mx = fmaxf(fmaxf(red[0], red[1]), fmaxf(red[2], red[3]));

  float e0 = __expf(v.x - mx), e1 = __expf(v.y - mx);
  float e2 = __expf(v.z - mx), e3 = __expf(v.w - mx);
  float sum = e0 + e1 + e2 + e3;
#pragma unroll
  for (int o = 32; o >= 1; o >>= 1) sum += __shfl_xor(sum, o);
  if (lane == 0) red[4 + w] = sum;
  __syncthreads();
  sum = red[4] + red[5] + red[6] + red[7];
  const float inv = 1.0f / sum;

  ushort4 o4;
  o4.x = f2bf(e0 * inv); o4.y = f2bf(e1 * inv);
  o4.z = f2bf(e2 * inv); o4.w = f2bf(e3 * inv);
  ((ushort4*)p)[tid] = o4;
}

// ---- V transpose: VT[z][e][t] = src[h*hStr + b*bStr + t*tStr + e], z=h*8+b ---
__global__ __launch_bounds__(256)
void transpose_v(const unsigned short* __restrict__ src, unsigned short* __restrict__ VT,
                 long tStr, long hStr, long bStr)
{
  const int z = blockIdx.z;
  const int hh = z >> 3, b = z & 7;
  const unsigned short* s = src + hh * hStr + b * bStr;
  __shared__ unsigned short tile[32][33];
  const int t0 = blockIdx.x * 32, e0 = blockIdx.y * 32;
  const int tx = threadIdx.x & 31, ty = threadIdx.x >> 5;
#pragma unroll
  for (int i = 0; i < 4; ++i) {
    const int tr = ty + i * 8;
    tile[tr][tx] = s[(long)(t0 + tr) * tStr + e0 + tx];
  }
  __syncthreads();
#pragma unroll
  for (int i = 0; i < 4; ++i) {
    const int er = ty + i * 8;
    VT[(long)z * 1048576 + (long)(e0 + er) * 1024 + t0 + tx] = tile[tx][er];
  }
}

// ---------------- converters / epilogue add -----------------------------------
__global__ __launch_bounds__(256)
void conv_bf16(const float* __restrict__ in, unsigned short* __restrict__ out, long n4)
{
  const long i = (long)blockIdx.x * 256 + threadIdx.x;
  if (i >= n4) return;
  const float4 v = ((const float4*)in)[i];
  ushort4 o; o.x = f2bf(v.x); o.y = f2bf(v.y); o.z = f2bf(v.z); o.w = f2bf(v.w);
  ((ushort4*)out)[i] = o;
}

// w_out [h][f][e] -> Wob[f][h*1024+e]
__global__ __launch_bounds__(256)
void conv_wout(const float* __restrict__ in, unsigned short* __restrict__ out)
{
  const long i = (long)blockIdx.x * 256 + threadIdx.x;   // 2M float4s
  const long o = i << 2;
  const long f = o >> 13, r = o & 8191;
  const long h = r >> 10, e = r & 1023;
  const float4 v = *(const float4*)(in + h * 1048576 + f * 1024 + e);
  ushort4 u; u.x = f2bf(v.x); u.y = f2bf(v.y); u.z = f2bf(v.z); u.w = f2bf(v.w);
  *(ushort4*)(out + o) = u;
}

__global__ __launch_bounds__(256)
void bias_sum_k(const float* __restrict__ b_out, float* __restrict__ bsum)
{
  const int f = blockIdx.x * 256 + threadIdx.x;
  if (f < 1024) {
    float s = 0.f;
#pragma unroll
    for (int h = 0; h < 8; ++h) s += b_out[h * 1024 + f];
    bsum[f] = s;
  }
}

// out = p[0] + p[1] + bsum   (2M float4)
__global__ __launch_bounds__(256)
void add_out_k(const float* __restrict__ p, float* __restrict__ out,
               const float* __restrict__ bsum)
{
  const long i = (long)blockIdx.x * 256 + threadIdx.x;
  const float4 a = ((const float4*)p)[i];
  const float4 b = ((const float4*)(p + 8388608))[i];
  const float4 s = ((const float4*)bsum)[i & 255];
  float4 o;
  o.x = a.x + b.x + s.x; o.y = a.y + b.y + s.y;
  o.z = a.z + b.z + s.z; o.w = a.w + b.w + s.w;
  ((float4*)out)[i] = o;
}

// ---------------- launch ------------------------------------------------------
extern "C" void kernel_launch(void* const* d_in, const int* in_sizes, int n_in,
                              void* d_out, int out_size, void* d_ws, size_t ws_size,
                              hipStream_t stream)
{
  const float* x     = (const float*)d_in[0];
  const float* w_in  = (const float*)d_in[1];
  const float* b_in  = (const float*)d_in[2];
  const float* w_out = (const float*)d_in[3];
  const float* b_out = (const float*)d_in[4];
  float* out = (float*)d_out;

  char* ws = (char*)d_ws;
  const long MB = 1ll << 20;
  unsigned short* Xb   = (unsigned short*)(ws);              // 16 MiB
  unsigned short* Wob  = (unsigned short*)(ws + 16 * MB);    // 16 MiB
  float*          bsum = (float*)         (ws + 32 * MB);    // 4 KiB
  unsigned short* Ocat = (unsigned short*)(ws + 33 * MB);    // 128 MiB
  unsigned short* Wbg  = (unsigned short*)(ws + 161 * MB);   // 12 MiB
  unsigned short* QKVg = (unsigned short*)(ws + 173 * MB);   // 96 MiB
  float*          SCg  = (float*)         (ws + 269 * MB);   // 64 MiB
  unsigned short* Pg   = (unsigned short*)(ws + 333 * MB);   // 32 MiB -> 365 MiB
  unsigned short* VT   = (unsigned short*)SCg;               // alias (SC dead post-softmax)
  float*          Opart = (float*)        (ws + 269 * MB);   // 64 MiB alias (post-attention)

  dim3 blk(256), blk512(512);

  conv_bf16 <<<8192, blk, 0, stream>>>(x, Xb, 2097152);
  conv_wout <<<8192, blk, 0, stream>>>(w_out, Wob);
  bias_sum_k<<<4,    blk, 0, stream>>>(b_out, bsum);

  for (int g = 0; g < 4; ++g) {
    // weights for heads 2g, 2g+1: [6144][1024] bf16
    conv_bf16<<<6144, blk, 0, stream>>>(w_in + (long)g * 6291456, Wbg, 1572864);

    // QKVg[sb][hh*3072 + sec*1024 + e] = Xb @ Wbg^T + b_in[g-rows]
    // persistent multi-tile: 256 blocks x 3 nt-tiles
    gemm256_qkv<<<256, blk512, 0, stream>>>(Xb, Wbg, QKVg, b_in + (long)g * 6144);

    // scores: z = hh*8+b: SCg[z][s][t] = (Q K^T)/32, fp32 (256 blocks, 1/CU)
    gemm256_nt<0,0,0><<<256, blk512, 0, stream>>>(
        QKVg, QKVg + 1024, SCg, nullptr, 0.03125f, 1024,
        49152, 49152, 1024,  3072, 6144,  3072, 6144,  8388608, 1048576,  4, 4, 8);

    softmax_k<<<16384, blk, 0, stream>>>(SCg, Pg);

    // VT[z][e][t] = V[(t*8+b)*6144 + hh*3072 + 2048 + e]
    transpose_v<<<dim3(32, 32, 16), blk, 0, stream>>>(
        QKVg + 2048, VT, 49152, 3072, 6144);

    // PV: Ocat[(s*8+b)*8192 + (2g+hh)*1024 + e] = sum_t P[z][s][t] VT[z][e][t]
    gemm256_nt<1,0,0><<<256, blk512, 0, stream>>>(
        Pg, VT, Ocat + (long)g * 2048, nullptr, 1.0f, 1024,
        1024, 1024, 65536,  8388608, 1048576,  8388608, 1048576,  1024, 8192,  4, 4, 8);
  }

  // outproj K-split: Opart[z] = Ocat[:, z*4096:(z+1)*4096] @ Wob[:, same]^T
  gemm256_nt<0,0,1><<<256, blk512, 0, stream>>>(
      Ocat, Wob, Opart, nullptr, 1.0f, 4096,
      8192, 8192, 1024,  0, 4096,  0, 4096,  0, 8388608,  32, 4, 2);

  add_out_k<<<8192, blk, 0, stream>>>(Opart, out, bsum);
}